// Round 1
// 208.356 us; speedup vs baseline: 1.2616x; 1.2616x over previous
//
#include <hip/hip_runtime.h>
#include <hip/hip_bf16.h>

typedef unsigned short u16;
typedef unsigned int u32;
typedef unsigned long long u64;
typedef short bf16x8 __attribute__((ext_vector_type(8)));
typedef float f32x4  __attribute__((ext_vector_type(4)));

// RowLSTM B=32, Cin=3, H=W=64, HC=128, gates o,f,i,g (all sigmoid), c=f*c+i*g,
// h=o*tanh(c). Masked-B 1x3 conv: taps (w-1, w).
//
// Round 8: same GEMM structure as round 7 (128 blocks = 4 w-quarters x 32 batch,
// 512 thr, mfma_f32_16x16x32_bf16, h recirculates in LDS, 1 barrier/row).
// Comms restructured OFF the per-row critical path:
//  - flag semantics: flag==R  <=>  halo rows 0..R-1 visible. Producer publishes
//    flag=r DURING row r, after elementwise but BEFORE this row's halo/out
//    stores -> the per-wave s_waitcnt vmcnt(0) only covers >=1-row-old stores
//    (~0 stall), instead of draining this row's HBM out-stores.
//  - consumer receives halo row r at TOP of row r: flag value PREFETCHED last
//    row (register compare in steady state), halo data load issued at top and
//    consumed after elementwise -> ~800cy cross-XCD latency hides under GEMM.
//    Miss -> spin fallback (consumer drops further behind producer, then the
//    prefetch hits; constant ~2-row pipeline offset, no per-row cost).
//  - x K-tile staging moved to wave 1 (top of row), off wave 0's path.
//  - bias hoisted into registers (was 16 ds_read_b32 /lane/row).

__device__ __forceinline__ u16 f2b(float f) {
    return __builtin_bit_cast(u16, __float2bfloat16(f));
}
__device__ __forceinline__ float sigm(float x) {
    return __builtin_amdgcn_rcpf(1.0f + __expf(-x));
}
__device__ __forceinline__ float tanh_fast(float x) {
    return 1.0f - 2.0f * __builtin_amdgcn_rcpf(__expf(2.0f * x) + 1.0f);
}

#define LINE(kt, lane) (((kt) * 64 + (lane)) * 16)
#define BUFBYTES (9 * 64 * 16)   /* 9216 B per buffer */

__global__ __launch_bounds__(512, 2) void rowlstm_mfma5(
    const float* __restrict__ x,   const float* __restrict__ Wis,
    const float* __restrict__ bis, const float* __restrict__ Wss,
    const float* __restrict__ bss, const float* __restrict__ h0,
    const float* __restrict__ c0,  float* __restrict__ out,
    u32* flags, char* halo)
{
    __shared__ __align__(16) char lds_buf[2 * BUFBYTES];   // 18432 B
    __shared__ u16  lds_x[3 * 64 * 17];                    // 6528 B
    __shared__ float lds_bias[512];                        // 2048 B

    const int tid  = threadIdx.x;
    const int s    = blockIdx.x;            // w-quarter
    const int b    = blockIdx.y;            // batch
    const int wid  = tid >> 6;              // wave [0,8) = hc-tile
    const int lane = tid & 63;
    const int q    = lane >> 4;             // quad
    const int n    = lane & 15;             // w within quarter
    const int wbase = s * 16;

    u32* flg_my = flags + ((size_t)b * 4 + s) * 8;
    u32* flg_up = flags + ((size_t)b * 4 + (s > 0 ? s - 1 : 0)) * 8;
    char* hs_my = halo + (((size_t)b * 4 + s) * 64) * 256;
    char* hs_up = halo + (((size_t)b * 4 + (s > 0 ? s - 1 : 0)) * 64) * 256;

    // ---------- phase 0: zero both B buffers ----------
    for (int i = tid; i < 1152; i += 512)
        *(uint4*)(lds_buf + i * 16) = make_uint4(0, 0, 0, 0);
    __syncthreads();

    // ---------- phase 1: one-time staging ----------
    lds_bias[tid] = bis[tid] + bss[tid];

    // x -> LDS bf16: [cch][r][wl1], wl1 = local w + 1 (col 0 = left halo col)
    for (int i = tid; i < 3264; i += 512) {
        int cch = i / 1088, rem = i % 1088;
        int r = rem / 17, wl1 = rem % 17;
        int gw = wbase + wl1 - 1;
        lds_x[i] = (gw < 0) ? (u16)0
                 : f2b(x[(((size_t)b * 3 + cch) * 64 + r) * 64 + gw]);
    }

    // A-fragments (persist in regs): a[j]=tap1(ic=kt*16+q*4+j), a[4+j]=tap0
    bf16x8 afr[4][9];
    {
        #pragma unroll
        for (int g = 0; g < 4; ++g) {
            int oc = g * 128 + wid * 16 + n;           // m = n
            #pragma unroll
            for (int kt = 0; kt < 8; ++kt) {
                bf16x8 a;
                #pragma unroll
                for (int jj = 0; jj < 4; ++jj) {
                    int ic = kt * 16 + q * 4 + jj;
                    float2 wp = *(const float2*)&Wss[(size_t)(oc * 128 + ic) * 3];
                    a[jj]     = (short)f2b(wp.y);      // tap1 (center)
                    a[4 + jj] = (short)f2b(wp.x);      // tap0 (left)
                }
                afr[g][kt] = a;
            }
            bf16x8 ax = {0, 0, 0, 0, 0, 0, 0, 0};
            if (q == 0) {
                #pragma unroll
                for (int cch = 0; cch < 3; ++cch) {
                    float2 wp = *(const float2*)&Wis[(size_t)(oc * 3 + cch) * 3];
                    ax[cch]     = (short)f2b(wp.y);
                    ax[4 + cch] = (short)f2b(wp.x);
                }
            }
            afr[g][8] = ax;
        }
    }

    // c-state (fp32, registers) + h0 publish into buf0
    float cst[4];
    {
        u16 hw[4];
        #pragma unroll
        for (int reg = 0; reg < 4; ++reg) {
            int hc = wid * 16 + q * 4 + reg;
            int wg = wbase + n;
            cst[reg] = c0[hc * 64 + wg];
            hw[reg] = f2b(h0[hc * 64 + wg]);
        }
        u64 d01 = (u64)((u32)hw[0] | ((u32)hw[1] << 16))
                | ((u64)((u32)hw[2] | ((u32)hw[3] << 16)) << 32);
        *(u64*)(lds_buf + LINE(wid, lane)) = d01;               // tap1 halves
        int wl = n + 1;
        if (wl < 16)
            *(u64*)(lds_buf + LINE(wid, q * 16 + wl) + 8) = d01;
    }
    // s>0: left-edge tap0 column from h0[:, wbase-1] (h0 is known globally)
    if (s > 0 && tid < 32) {
        int ic0 = tid * 4;
        u64 v = (u64)((u32)f2b(h0[(ic0 + 0) * 64 + wbase - 1]) | ((u32)f2b(h0[(ic0 + 1) * 64 + wbase - 1]) << 16))
              | ((u64)((u32)f2b(h0[(ic0 + 2) * 64 + wbase - 1]) | ((u32)f2b(h0[(ic0 + 3) * 64 + wbase - 1]) << 16)) << 32);
        *(u64*)(lds_buf + LINE(tid >> 2, (tid & 3) * 16) + 8) = v;
    }
    // x K-tile for row 0 into buf0 (q==0 lanes only; q>0 lanes stay zero)
    if (tid < 16) {
        int nn = tid;
        u32 d0 = (u32)lds_x[0 * 1088 + 0 * 17 + nn + 1] | ((u32)lds_x[1 * 1088 + 0 * 17 + nn + 1] << 16);
        u32 d1 = (u32)lds_x[2 * 1088 + 0 * 17 + nn + 1];
        u32 d2 = (u32)lds_x[0 * 1088 + 0 * 17 + nn]     | ((u32)lds_x[1 * 1088 + 0 * 17 + nn] << 16);
        u32 d3 = (u32)lds_x[2 * 1088 + 0 * 17 + nn];
        *(uint4*)(lds_buf + LINE(8, nn)) = make_uint4(d0, d1, d2, d3);
    }
    __syncthreads();

    // bias -> registers (constant per lane across rows)
    f32x4 bias_r[4];
    #pragma unroll
    for (int g = 0; g < 4; ++g) {
        int oc = g * 128 + wid * 16 + q * 4;
        bias_r[g][0] = lds_bias[oc + 0];
        bias_r[g][1] = lds_bias[oc + 1];
        bias_r[g][2] = lds_bias[oc + 2];
        bias_r[g][3] = lds_bias[oc + 3];
    }

    u32 flag_seen = 0;   // meaningful in tid<32 lanes of s>0 blocks

    // ================= row loop: ONE barrier per row =================
    for (int r = 0; r < 64; ++r) {
        char* rbuf = lds_buf + (r & 1) * BUFBYTES;
        char* wbuf = lds_buf + ((r & 1) ^ 1) * BUFBYTES;

        // ---- top: consumer receive of halo row r (issue early, use late) ----
        u64 hv = 0; bool have = false;
        if (s > 0 && r < 63 && tid < 32) {
            u32 fs = flag_seen;
            while (fs <= (u32)r) {          // steady state: prefetched fs > r
                fs = __hip_atomic_load(&flg_up[tid >> 2], __ATOMIC_RELAXED,
                                       __HIP_MEMORY_SCOPE_AGENT);
                if (fs <= (u32)r) __builtin_amdgcn_s_sleep(1);
            }
            hv = __hip_atomic_load((u64*)(hs_up + (size_t)r * 256 + tid * 8),
                                   __ATOMIC_RELAXED, __HIP_MEMORY_SCOPE_AGENT);
            // prefetch flag for next row's check (off critical path)
            flag_seen = __hip_atomic_load(&flg_up[tid >> 2], __ATOMIC_RELAXED,
                                          __HIP_MEMORY_SCOPE_AGENT);
            have = true;
        }

        // ---- top: x K-tile for row r+1 into wbuf (wave 1, off wave 0) ----
        if (r < 63 && tid >= 64 && tid < 80) {
            int nn = tid - 64, r1 = r + 1;
            u32 d0 = (u32)lds_x[0 * 1088 + r1 * 17 + nn + 1] | ((u32)lds_x[1 * 1088 + r1 * 17 + nn + 1] << 16);
            u32 d1 = (u32)lds_x[2 * 1088 + r1 * 17 + nn + 1];
            u32 d2 = (u32)lds_x[0 * 1088 + r1 * 17 + nn]     | ((u32)lds_x[1 * 1088 + r1 * 17 + nn] << 16);
            u32 d3 = (u32)lds_x[2 * 1088 + r1 * 17 + nn];
            *(uint4*)(wbuf + LINE(8, nn)) = make_uint4(d0, d1, d2, d3);
        }

        // ---- GEMM ----
        f32x4 acc[4];
        acc[0] = bias_r[0]; acc[1] = bias_r[1];
        acc[2] = bias_r[2]; acc[3] = bias_r[3];
        #pragma unroll
        for (int kt = 0; kt < 9; ++kt) {
            bf16x8 bv = *(const bf16x8*)(rbuf + LINE(kt, lane));
            acc[0] = __builtin_amdgcn_mfma_f32_16x16x32_bf16(afr[0][kt], bv, acc[0], 0, 0, 0);
            acc[1] = __builtin_amdgcn_mfma_f32_16x16x32_bf16(afr[1][kt], bv, acc[1], 0, 0, 0);
            acc[2] = __builtin_amdgcn_mfma_f32_16x16x32_bf16(afr[2][kt], bv, acc[2], 0, 0, 0);
            acc[3] = __builtin_amdgcn_mfma_f32_16x16x32_bf16(afr[3][kt], bv, acc[3], 0, 0, 0);
        }

        // ---- elementwise (D: col = n, row = q*4+reg) ----
        float hval[4]; u16 hw[4];
        #pragma unroll
        for (int reg = 0; reg < 4; ++reg) {
            float o  = sigm(acc[0][reg]);
            float f  = sigm(acc[1][reg]);
            float ii = sigm(acc[2][reg]);
            float gg = sigm(acc[3][reg]);
            float cn = f * cst[reg] + ii * gg;
            cst[reg] = cn;
            float h = o * tanh_fast(cn);
            hval[reg] = h;
            hw[reg] = f2b(h);
        }

        // ---- publish flag=r (covers halo rows 0..r-1): all counted vmem ops
        //      are >=1 row old at this point -> vmcnt(0) is ~free ----
        if (s < 3 && r > 0 && lane == 15) {
            asm volatile("s_waitcnt vmcnt(0)" ::: "memory");
            __hip_atomic_store(&flg_my[wid], (u32)r,
                               __ATOMIC_RELAXED, __HIP_MEMORY_SCOPE_AGENT);
        }

        // ---- h -> LDS (wbuf) + right-edge halo store (fire, drained next row) ----
        u64 d01 = (u64)((u32)hw[0] | ((u32)hw[1] << 16))
                | ((u64)((u32)hw[2] | ((u32)hw[3] << 16)) << 32);
        *(u64*)(wbuf + LINE(wid, lane)) = d01;                 // tap1 halves
        int wl = n + 1;
        if (wl < 16)
            *(u64*)(wbuf + LINE(wid, q * 16 + wl) + 8) = d01;
        else if (s < 3 && r < 63)                              // right edge -> s+1
            __hip_atomic_store((u64*)(hs_my + (size_t)r * 256 + (wid * 4 + q) * 8),
                               d01, __ATOMIC_RELAXED, __HIP_MEMORY_SCOPE_AGENT);

        // ---- out stores (fire-and-forget; never waited on this row) ----
        #pragma unroll
        for (int reg = 0; reg < 4; ++reg) {
            int hc = wid * 16 + q * 4 + reg;
            out[(((size_t)(b * 128 + hc)) * 64 + r) * 64 + wbase + n] = hval[reg];
        }

        // ---- consumer: commit received halo into wbuf (load latency hidden) ----
        if (have)
            *(u64*)(wbuf + LINE(tid >> 2, (tid & 3) * 16) + 8) = hv;

        __syncthreads();
    }
}

extern "C" void kernel_launch(void* const* d_in, const int* in_sizes, int n_in,
                              void* d_out, int out_size, void* d_ws, size_t ws_size,
                              hipStream_t stream)
{
    const float* x   = (const float*)d_in[0];
    const float* Wis = (const float*)d_in[1];
    const float* bis = (const float*)d_in[2];
    const float* Wss = (const float*)d_in[3];
    const float* bss = (const float*)d_in[4];
    const float* h0  = (const float*)d_in[5];
    const float* c0  = (const float*)d_in[6];
    float* out = (float*)d_out;

    // flags: 32 b x 4 s x 8 wid u32 (4096 B); halo slots at +4096: 32*4*64*256 = 2 MB
    hipMemsetAsync(d_ws, 0, 4096, stream);
    rowlstm_mfma5<<<dim3(4, 32), 512, 0, stream>>>(
        x, Wis, bis, Wss, bss, h0, c0, out,
        (u32*)d_ws, (char*)d_ws + 4096);
}

// Round 2
// 204.661 us; speedup vs baseline: 1.2844x; 1.0181x over previous
//
#include <hip/hip_runtime.h>
#include <hip/hip_bf16.h>

typedef unsigned short u16;
typedef unsigned int u32;
typedef unsigned long long u64;
typedef short bf16x8 __attribute__((ext_vector_type(8)));
typedef float f32x4  __attribute__((ext_vector_type(4)));

// RowLSTM B=32, Cin=3, H=W=64, HC=128, gates o,f,i,g (all sigmoid), c=f*c+i*g,
// h=o*tanh(c). Masked-B 1x3 conv: taps (w-1, w).
//
// Round 9: (a) loop barrier relaxed to {s_waitcnt lgkmcnt(0); s_barrier} --
// __syncthreads' implicit vmcnt(0) was draining each row's 4 HBM out-stores
// (+halo store) on EVERY wave (~400-800cy store-ack stall per row).  The
// barrier only orders LDS; vmem ordering is carried by the explicit
// vmcnt(0)->flag protocol.  (b) halo production moved to wave 7: it reads the
// right-edge h column of rbuf (prev row, already in LDS), stores it to the
// halo buffer, and publishes a single block-level flag at row TOP where its
// only outstanding vmem ops are >=1-row-old stores (vmcnt(0) ~free; wave 7
// never issues vmem loads).  Wave 0 is now a pure consumer: its halo-data
// load (issued at row top, consumed at row bottom) is never force-drained.
// Flag semantics: flag==F  <=>  halo slots 0..F-1 visible; slot t-1 is stored
// during row t, certified at row t+1 top (publish F=r-1), final F=63 post-loop.

__device__ __forceinline__ u16 f2b(float f) {
    return __builtin_bit_cast(u16, __float2bfloat16(f));
}
__device__ __forceinline__ float sigm(float x) {
    return __builtin_amdgcn_rcpf(1.0f + __expf(-x));
}
__device__ __forceinline__ float tanh_fast(float x) {
    return 1.0f - 2.0f * __builtin_amdgcn_rcpf(__expf(2.0f * x) + 1.0f);
}

#define LINE(kt, lane) (((kt) * 64 + (lane)) * 16)
#define BUFBYTES (9 * 64 * 16)   /* 9216 B per buffer */

__global__ __launch_bounds__(512, 2) void rowlstm_mfma6(
    const float* __restrict__ x,   const float* __restrict__ Wis,
    const float* __restrict__ bis, const float* __restrict__ Wss,
    const float* __restrict__ bss, const float* __restrict__ h0,
    const float* __restrict__ c0,  float* __restrict__ out,
    u32* flags, char* halo)
{
    __shared__ __align__(16) char lds_buf[2 * BUFBYTES];   // 18432 B
    __shared__ u16  lds_x[3 * 64 * 17];                    // 6528 B
    __shared__ float lds_bias[512];                        // 2048 B

    const int tid  = threadIdx.x;
    const int s    = blockIdx.x;            // w-quarter
    const int b    = blockIdx.y;            // batch
    const int wid  = tid >> 6;              // wave [0,8) = hc-tile
    const int lane = tid & 63;
    const int q    = lane >> 4;             // quad
    const int n    = lane & 15;             // w within quarter
    const int wbase = s * 16;

    u32* flg_my = flags + ((size_t)b * 4 + s) * 8;
    u32* flg_up = flags + ((size_t)b * 4 + (s > 0 ? s - 1 : 0)) * 8;
    char* hs_my = halo + (((size_t)b * 4 + s) * 64) * 256;
    char* hs_up = halo + (((size_t)b * 4 + (s > 0 ? s - 1 : 0)) * 64) * 256;

    // ---------- phase 0: zero both B buffers ----------
    for (int i = tid; i < 1152; i += 512)
        *(uint4*)(lds_buf + i * 16) = make_uint4(0, 0, 0, 0);
    __syncthreads();

    // ---------- phase 1: one-time staging ----------
    lds_bias[tid] = bis[tid] + bss[tid];

    // x -> LDS bf16: [cch][r][wl1], wl1 = local w + 1 (col 0 = left halo col)
    for (int i = tid; i < 3264; i += 512) {
        int cch = i / 1088, rem = i % 1088;
        int r = rem / 17, wl1 = rem % 17;
        int gw = wbase + wl1 - 1;
        lds_x[i] = (gw < 0) ? (u16)0
                 : f2b(x[(((size_t)b * 3 + cch) * 64 + r) * 64 + gw]);
    }

    // A-fragments (persist in regs): a[j]=tap1(ic=kt*16+q*4+j), a[4+j]=tap0
    bf16x8 afr[4][9];
    {
        #pragma unroll
        for (int g = 0; g < 4; ++g) {
            int oc = g * 128 + wid * 16 + n;           // m = n
            #pragma unroll
            for (int kt = 0; kt < 8; ++kt) {
                bf16x8 a;
                #pragma unroll
                for (int jj = 0; jj < 4; ++jj) {
                    int ic = kt * 16 + q * 4 + jj;
                    float2 wp = *(const float2*)&Wss[(size_t)(oc * 128 + ic) * 3];
                    a[jj]     = (short)f2b(wp.y);      // tap1 (center)
                    a[4 + jj] = (short)f2b(wp.x);      // tap0 (left)
                }
                afr[g][kt] = a;
            }
            bf16x8 ax = {0, 0, 0, 0, 0, 0, 0, 0};
            if (q == 0) {
                #pragma unroll
                for (int cch = 0; cch < 3; ++cch) {
                    float2 wp = *(const float2*)&Wis[(size_t)(oc * 3 + cch) * 3];
                    ax[cch]     = (short)f2b(wp.y);
                    ax[4 + cch] = (short)f2b(wp.x);
                }
            }
            afr[g][8] = ax;
        }
    }

    // c-state (fp32, registers) + h0 publish into buf0
    float cst[4];
    {
        u16 hw[4];
        #pragma unroll
        for (int reg = 0; reg < 4; ++reg) {
            int hc = wid * 16 + q * 4 + reg;
            int wg = wbase + n;
            cst[reg] = c0[hc * 64 + wg];
            hw[reg] = f2b(h0[hc * 64 + wg]);
        }
        u64 d01 = (u64)((u32)hw[0] | ((u32)hw[1] << 16))
                | ((u64)((u32)hw[2] | ((u32)hw[3] << 16)) << 32);
        *(u64*)(lds_buf + LINE(wid, lane)) = d01;               // tap1 halves
        int wl = n + 1;
        if (wl < 16)
            *(u64*)(lds_buf + LINE(wid, q * 16 + wl) + 8) = d01;
    }
    // s>0: left-edge tap0 column from h0[:, wbase-1] (h0 is known globally)
    if (s > 0 && tid < 32) {
        int ic0 = tid * 4;
        u64 v = (u64)((u32)f2b(h0[(ic0 + 0) * 64 + wbase - 1]) | ((u32)f2b(h0[(ic0 + 1) * 64 + wbase - 1]) << 16))
              | ((u64)((u32)f2b(h0[(ic0 + 2) * 64 + wbase - 1]) | ((u32)f2b(h0[(ic0 + 3) * 64 + wbase - 1]) << 16)) << 32);
        *(u64*)(lds_buf + LINE(tid >> 2, (tid & 3) * 16) + 8) = v;
    }
    // x K-tile for row 0 into buf0 (q==0 lanes only; q>0 lanes stay zero)
    if (tid < 16) {
        int nn = tid;
        u32 d0 = (u32)lds_x[0 * 1088 + 0 * 17 + nn + 1] | ((u32)lds_x[1 * 1088 + 0 * 17 + nn + 1] << 16);
        u32 d1 = (u32)lds_x[2 * 1088 + 0 * 17 + nn + 1];
        u32 d2 = (u32)lds_x[0 * 1088 + 0 * 17 + nn]     | ((u32)lds_x[1 * 1088 + 0 * 17 + nn] << 16);
        u32 d3 = (u32)lds_x[2 * 1088 + 0 * 17 + nn];
        *(uint4*)(lds_buf + LINE(8, nn)) = make_uint4(d0, d1, d2, d3);
    }
    __syncthreads();

    // bias -> registers (constant per lane across rows)
    f32x4 bias_r[4];
    #pragma unroll
    for (int g = 0; g < 4; ++g) {
        int oc = g * 128 + wid * 16 + q * 4;
        bias_r[g][0] = lds_bias[oc + 0];
        bias_r[g][1] = lds_bias[oc + 1];
        bias_r[g][2] = lds_bias[oc + 2];
        bias_r[g][3] = lds_bias[oc + 3];
    }

    u32 flag_seen = 0;   // meaningful in tid<32 lanes of s>0 blocks

    // ================= row loop: ONE relaxed barrier per row =================
    for (int r = 0; r < 64; ++r) {
        char* rbuf = lds_buf + (r & 1) * BUFBYTES;
        char* wbuf = lds_buf + ((r & 1) ^ 1) * BUFBYTES;

        // ---- wave 7: halo producer + publisher (never issues vmem loads) ----
        if (s < 3 && wid == 7 && lane < 32) {
            // publish flag=r-1 (certifies slots 0..r-2; their stores are
            // >=1 row old -> in-order retirement makes vmcnt(0) ~free)
            if (r >= 2 && lane == 0) {
                asm volatile("s_waitcnt vmcnt(0)" ::: "memory");
                __hip_atomic_store(&flg_my[0], (u32)(r - 1),
                                   __ATOMIC_RELAXED, __HIP_MEMORY_SCOPE_AGENT);
            }
            // read right-edge h column of row r-1 from rbuf, store slot r-1
            if (r >= 1) {
                u64 ev = *(const u64*)(rbuf + LINE(lane >> 2, (lane & 3) * 16 + 15));
                __hip_atomic_store((u64*)(hs_my + (size_t)(r - 1) * 256 + lane * 8),
                                   ev, __ATOMIC_RELAXED, __HIP_MEMORY_SCOPE_AGENT);
            }
        }

        // ---- wave 0 (tid<32): pure consumer; receive halo row r ----
        u64 hv = 0; bool have = false;
        if (s > 0 && r < 63 && tid < 32) {
            u32 fs = flag_seen;
            while (fs <= (u32)r) {          // steady state: prefetched fs > r
                fs = __hip_atomic_load(&flg_up[0], __ATOMIC_RELAXED,
                                       __HIP_MEMORY_SCOPE_AGENT);
                if (fs <= (u32)r) __builtin_amdgcn_s_sleep(1);
            }
            hv = __hip_atomic_load((u64*)(hs_up + (size_t)r * 256 + tid * 8),
                                   __ATOMIC_RELAXED, __HIP_MEMORY_SCOPE_AGENT);
            // prefetch flag for next row's check (off critical path)
            flag_seen = __hip_atomic_load(&flg_up[0], __ATOMIC_RELAXED,
                                          __HIP_MEMORY_SCOPE_AGENT);
            have = true;
        }

        // ---- wave 1: x K-tile for row r+1 into wbuf ----
        if (r < 63 && tid >= 64 && tid < 80) {
            int nn = tid - 64, r1 = r + 1;
            u32 d0 = (u32)lds_x[0 * 1088 + r1 * 17 + nn + 1] | ((u32)lds_x[1 * 1088 + r1 * 17 + nn + 1] << 16);
            u32 d1 = (u32)lds_x[2 * 1088 + r1 * 17 + nn + 1];
            u32 d2 = (u32)lds_x[0 * 1088 + r1 * 17 + nn]     | ((u32)lds_x[1 * 1088 + r1 * 17 + nn] << 16);
            u32 d3 = (u32)lds_x[2 * 1088 + r1 * 17 + nn];
            *(uint4*)(wbuf + LINE(8, nn)) = make_uint4(d0, d1, d2, d3);
        }

        // ---- GEMM ----
        f32x4 acc[4];
        acc[0] = bias_r[0]; acc[1] = bias_r[1];
        acc[2] = bias_r[2]; acc[3] = bias_r[3];
        #pragma unroll
        for (int kt = 0; kt < 9; ++kt) {
            bf16x8 bv = *(const bf16x8*)(rbuf + LINE(kt, lane));
            acc[0] = __builtin_amdgcn_mfma_f32_16x16x32_bf16(afr[0][kt], bv, acc[0], 0, 0, 0);
            acc[1] = __builtin_amdgcn_mfma_f32_16x16x32_bf16(afr[1][kt], bv, acc[1], 0, 0, 0);
            acc[2] = __builtin_amdgcn_mfma_f32_16x16x32_bf16(afr[2][kt], bv, acc[2], 0, 0, 0);
            acc[3] = __builtin_amdgcn_mfma_f32_16x16x32_bf16(afr[3][kt], bv, acc[3], 0, 0, 0);
        }

        // ---- elementwise (D: col = n, row = q*4+reg) ----
        float hval[4]; u16 hw[4];
        #pragma unroll
        for (int reg = 0; reg < 4; ++reg) {
            float o  = sigm(acc[0][reg]);
            float f  = sigm(acc[1][reg]);
            float ii = sigm(acc[2][reg]);
            float gg = sigm(acc[3][reg]);
            float cn = f * cst[reg] + ii * gg;
            cst[reg] = cn;
            float h = o * tanh_fast(cn);
            hval[reg] = h;
            hw[reg] = f2b(h);
        }

        // ---- h -> LDS (wbuf); edge halo now handled by wave 7 next row ----
        u64 d01 = (u64)((u32)hw[0] | ((u32)hw[1] << 16))
                | ((u64)((u32)hw[2] | ((u32)hw[3] << 16)) << 32);
        *(u64*)(wbuf + LINE(wid, lane)) = d01;                 // tap1 halves
        int wl = n + 1;
        if (wl < 16)
            *(u64*)(wbuf + LINE(wid, q * 16 + wl) + 8) = d01;

        // ---- out stores (fire-and-forget; never drained by the barrier) ----
        #pragma unroll
        for (int reg = 0; reg < 4; ++reg) {
            int hc = wid * 16 + q * 4 + reg;
            out[(((size_t)(b * 128 + hc)) * 64 + r) * 64 + wbase + n] = hval[reg];
        }

        // ---- consumer: commit received halo into wbuf (latency hidden) ----
        if (have)
            *(u64*)(wbuf + LINE(tid >> 2, (tid & 3) * 16) + 8) = hv;

        // ---- relaxed barrier: order LDS only (no vmem drain) ----
        __builtin_amdgcn_sched_barrier(0);
        asm volatile("s_waitcnt lgkmcnt(0)\n\ts_barrier" ::: "memory");
        __builtin_amdgcn_sched_barrier(0);
    }

    // final publish: certify slot 62 (stored during row 63)
    if (s < 3 && tid == 448) {
        asm volatile("s_waitcnt vmcnt(0)" ::: "memory");
        __hip_atomic_store(&flg_my[0], 63u,
                           __ATOMIC_RELAXED, __HIP_MEMORY_SCOPE_AGENT);
    }
}

extern "C" void kernel_launch(void* const* d_in, const int* in_sizes, int n_in,
                              void* d_out, int out_size, void* d_ws, size_t ws_size,
                              hipStream_t stream)
{
    const float* x   = (const float*)d_in[0];
    const float* Wis = (const float*)d_in[1];
    const float* bis = (const float*)d_in[2];
    const float* Wss = (const float*)d_in[3];
    const float* bss = (const float*)d_in[4];
    const float* h0  = (const float*)d_in[5];
    const float* c0  = (const float*)d_in[6];
    float* out = (float*)d_out;

    // flags: 32 b x 4 s x 8 u32 (4096 B); halo slots at +4096: 32*4*64*256 = 2 MB
    hipMemsetAsync(d_ws, 0, 4096, stream);
    rowlstm_mfma6<<<dim3(4, 32), 512, 0, stream>>>(
        x, Wis, bis, Wss, bss, h0, c0, out,
        (u32*)d_ws, (char*)d_ws + 4096);
}